// Round 3
// baseline (198.025 us; speedup 1.0000x reference)
//
#include <hip/hip_runtime.h>
#include <math.h>

#define MOM 0.999f
#define ONE_M_MOM 0.001f
#define INV_TEMP (1.0f / 0.07f)
#define C_CLASSES 20000
#define B_SZ 512
#define DE 512
#define PART_ROW 2048                       // K * Dp = 8 * 256
#define PART_BANK_N (C_CLASSES * PART_ROW)  // 40,960,000 floats
#define EMB_BANK_N (C_CLASSES * DE)         // 10,240,000 floats
#define NEG_INF (-3.0e38f)
#define NTILE 157         // ceil(20000/128)
#define NT2 (NTILE * 2)   // 314 half-tiles per row

typedef __attribute__((ext_vector_type(8))) short short8;
typedef __attribute__((ext_vector_type(4))) float f32x4;

__device__ inline unsigned short f2bf_rne(float f) {
    unsigned u = __builtin_bit_cast(unsigned, f);
    return (unsigned short)((u + 0x7FFFu + ((u >> 16) & 1u)) >> 16);
}

__device__ inline void gload16(const void* g, void* l) {
    __builtin_amdgcn_global_load_lds(
        (const __attribute__((address_space(1))) unsigned int*)g,
        (__attribute__((address_space(3))) unsigned int*)l, 16, 0, 0);
}

// --------- normalize embeddings -> q_hat fp32 + A bf16; scatter inv_map
__global__ void qnorm_conv(const float* __restrict__ emb, const int* __restrict__ labels,
                           float* __restrict__ q_hat, unsigned short* __restrict__ Ab,
                           int* __restrict__ inv_map) {
    int b = blockIdx.x;
    int l = threadIdx.x;  // 64
    if (l == 0) inv_map[labels[b]] = b;  // inv_map pre-filled with -1
    const float4* row = (const float4*)(emb + (long)b * DE);
    float4 v0 = row[2 * l], v1 = row[2 * l + 1];
    float ss = v0.x * v0.x + v0.y * v0.y + v0.z * v0.z + v0.w * v0.w
             + v1.x * v1.x + v1.y * v1.y + v1.z * v1.z + v1.w * v1.w;
#pragma unroll
    for (int off = 32; off; off >>= 1) ss += __shfl_xor(ss, off);
    float inv = 1.0f / fmaxf(sqrtf(ss), 1e-12f);
    v0.x *= inv; v0.y *= inv; v0.z *= inv; v0.w *= inv;
    v1.x *= inv; v1.y *= inv; v1.z *= inv; v1.w *= inv;
    float4* out = (float4*)(q_hat + (long)b * DE);
    out[2 * l] = v0; out[2 * l + 1] = v1;
    short8 o;
    o[0] = (short)f2bf_rne(v0.x); o[1] = (short)f2bf_rne(v0.y);
    o[2] = (short)f2bf_rne(v0.z); o[3] = (short)f2bf_rne(v0.w);
    o[4] = (short)f2bf_rne(v1.x); o[5] = (short)f2bf_rne(v1.y);
    o[6] = (short)f2bf_rne(v1.z); o[7] = (short)f2bf_rne(v1.w);
    *(short8*)(Ab + (long)b * DE + l * 8) = o;
}

// --------- part bank: single-pass copy + EMA (row-labeled)
__global__ void part_pass(const float4* __restrict__ pb, const float4* __restrict__ pf,
                          const int* __restrict__ inv_map, float4* __restrict__ out_pb) {
    int c = blockIdx.x;  // 20000
    int t = threadIdx.x; // 256
    long base = (long)c * (PART_ROW / 4);
    int mb = inv_map[c];
    if (mb >= 0) {
        const float4* src = pf + (long)mb * (PART_ROW / 4);
#pragma unroll
        for (int it = 0; it < 2; ++it) {
            int j = t + it * 256;
            float4 o = pb[base + j], n = src[j], r;
            r.x = MOM * o.x + ONE_M_MOM * n.x;
            r.y = MOM * o.y + ONE_M_MOM * n.y;
            r.z = MOM * o.z + ONE_M_MOM * n.z;
            r.w = MOM * o.w + ONE_M_MOM * n.w;
            out_pb[base + j] = r;
        }
    } else {
#pragma unroll
        for (int it = 0; it < 2; ++it) {
            int j = t + it * 256;
            out_pb[base + j] = pb[base + j];
        }
    }
}

// --------- embed bank: copy + EMA + row norm + bf16, single pass
__global__ void embed_pass(const float* __restrict__ ebank, const float* __restrict__ emb,
                           const int* __restrict__ inv_map, float* __restrict__ out_eb,
                           unsigned short* __restrict__ Bb, float* __restrict__ inv_norm) {
    int w = threadIdx.x >> 6, l = threadIdx.x & 63;
    int c = blockIdx.x * 4 + w;  // < 20000
    const float4* row = (const float4*)(ebank + ((long)c << 9));
    float4 v0 = row[2 * l], v1 = row[2 * l + 1];
    int mb = inv_map[c];
    if (mb >= 0) {
        const float4* nr = (const float4*)(emb + ((long)mb << 9));
        float4 n0 = nr[2 * l], n1 = nr[2 * l + 1];
        v0.x = MOM * v0.x + ONE_M_MOM * n0.x;
        v0.y = MOM * v0.y + ONE_M_MOM * n0.y;
        v0.z = MOM * v0.z + ONE_M_MOM * n0.z;
        v0.w = MOM * v0.w + ONE_M_MOM * n0.w;
        v1.x = MOM * v1.x + ONE_M_MOM * n1.x;
        v1.y = MOM * v1.y + ONE_M_MOM * n1.y;
        v1.z = MOM * v1.z + ONE_M_MOM * n1.z;
        v1.w = MOM * v1.w + ONE_M_MOM * n1.w;
    }
    float4* orow = (float4*)(out_eb + ((long)c << 9));
    orow[2 * l] = v0; orow[2 * l + 1] = v1;
    float ss = v0.x * v0.x + v0.y * v0.y + v0.z * v0.z + v0.w * v0.w
             + v1.x * v1.x + v1.y * v1.y + v1.z * v1.z + v1.w * v1.w;
#pragma unroll
    for (int off = 32; off; off >>= 1) ss += __shfl_xor(ss, off);
    if (l == 0) inv_norm[c] = 1.0f / fmaxf(sqrtf(ss), 1e-12f);
    short8 o;
    o[0] = (short)f2bf_rne(v0.x); o[1] = (short)f2bf_rne(v0.y);
    o[2] = (short)f2bf_rne(v0.z); o[3] = (short)f2bf_rne(v0.w);
    o[4] = (short)f2bf_rne(v1.x); o[5] = (short)f2bf_rne(v1.y);
    o[6] = (short)f2bf_rne(v1.z); o[7] = (short)f2bf_rne(v1.w);
    *(short8*)(Bb + ((long)c << 9) + l * 8) = o;
}

// --------- MFMA GEMM + fused per-tile top-16 partials
// A bf16 [512][512], B bf16 [20000][512]. Tile 128x128, 4 waves.
// Epilogue: scaled sim -> LDS tile -> per-row-half top-16 -> partials.
__global__ void __launch_bounds__(256)
gemm_topk(const unsigned short* __restrict__ A, const unsigned short* __restrict__ B,
          const float* __restrict__ inv_norm, const int* __restrict__ labels,
          float* __restrict__ partials) {
    __shared__ float stile[128 * 130];  // 66,560 B; first 16 KB doubles as staging
    unsigned short* Asm = (unsigned short*)stile;         // 128*32 u16 = 8 KB
    unsigned short* Bsm = (unsigned short*)stile + 4096;  // 8 KB

    const int t = threadIdx.x;
    const int w = t >> 6, l = t & 63;
    const int wr = w >> 1, wc = w & 1;
    const int bm = blockIdx.x, bn = blockIdx.y;

    f32x4 acc[4][4] = {};

    const int srow = t >> 2;
    const int sk = (t & 3) << 3;
    const unsigned short* Ab0 = A + ((long)(bm * 128 + srow) << 9) + sk;
    const unsigned short* Ab1 = Ab0 + ((long)64 << 9);
    int br0 = bn * 128 + srow; if (br0 > C_CLASSES - 1) br0 = C_CLASSES - 1;
    int br1 = bn * 128 + srow + 64; if (br1 > C_CLASSES - 1) br1 = C_CLASSES - 1;
    const unsigned short* Bb0 = B + ((long)br0 << 9) + sk;
    const unsigned short* Bb1 = B + ((long)br1 << 9) + sk;

    char* Al = (char*)Asm + (w << 10);
    char* Bl = (char*)Bsm + (w << 10);

    const int fr = l & 15;
    const int fk = (l >> 4) << 3;

    for (int kt = 0; kt < 16; ++kt) {
        const int ko = kt << 5;
        gload16(Ab0 + ko, Al);
        gload16(Ab1 + ko, Al + 4096);
        gload16(Bb0 + ko, Bl);
        gload16(Bb1 + ko, Bl + 4096);
        __syncthreads();
        const unsigned short* Ap = Asm + (((wr * 64) + fr) << 5) + fk;
        const unsigned short* Bp = Bsm + (((wc * 64) + fr) << 5) + fk;
        short8 af[4], bfr[4];
#pragma unroll
        for (int m = 0; m < 4; ++m) af[m] = *(const short8*)(Ap + (m << 9));
#pragma unroll
        for (int n = 0; n < 4; ++n) bfr[n] = *(const short8*)(Bp + (n << 9));
#pragma unroll
        for (int m = 0; m < 4; ++m)
#pragma unroll
            for (int n = 0; n < 4; ++n)
                acc[m][n] = __builtin_amdgcn_mfma_f32_16x16x32_bf16(af[m], bfr[n], acc[m][n], 0, 0, 0);
        __syncthreads();
    }

    // ---- dump scaled sim into LDS tile (C/D: col=lane&15, row=(lane>>4)*4+j)
    const int r4 = (l >> 4) << 2;
#pragma unroll
    for (int n = 0; n < 4; ++n) {
        int ct = wc * 64 + fr + n * 16;  // col in tile
        int cg = bn * 128 + ct;
        bool ok = cg < C_CLASSES;
        float sc = ok ? inv_norm[cg] * INV_TEMP : 0.0f;
#pragma unroll
        for (int m = 0; m < 4; ++m) {
            int rt = wr * 64 + r4 + m * 16;
#pragma unroll
            for (int j = 0; j < 4; ++j)
                stile[(rt + j) * 130 + ct] = ok ? acc[m][n][j] * sc : NEG_INF;
        }
    }
    __syncthreads();

    // ---- per-row half-tile top-16
    const int r = t >> 1, half = t & 1;
    const int gr = bm * 128 + r;          // < 512 always
    const int lab = labels[gr];
    const int lab_l = lab - (bn << 7) - (half << 6);  // local col of positive, if in range
    const float* bp = stile + r * 130 + half * 64;
    float tl[16];
#pragma unroll
    for (int j = 0; j < 16; ++j) tl[j] = NEG_INF;
    for (int c = 0; c < 64; ++c) {
        if (c == lab_l) continue;
        float v = bp[c];
        if (v > tl[15]) {
            tl[15] = v;
#pragma unroll
            for (int j = 15; j > 0; --j) {
                float a = tl[j - 1], bb = tl[j];
                if (bb > a) { tl[j - 1] = bb; tl[j] = a; }
            }
        }
    }
    float* op = partials + ((long)gr * NT2 + (bn << 1) + half) * 16;
#pragma unroll
    for (int j = 0; j < 16; ++j) op[j] = tl[j];
}

// --------- merge partials -> top-16 global; pos via fp32 dot; logsumexp
__global__ void merge_nce(const float* __restrict__ partials, const float* __restrict__ q_hat,
                          const float* __restrict__ out_eb, const float* __restrict__ inv_norm,
                          const int* __restrict__ labels, float* __restrict__ lnce) {
    int b = blockIdx.x;
    int t = threadIdx.x;  // 256
    const float* pr = partials + (long)b * (NT2 * 16);

    float tl[16];
#pragma unroll
    for (int j = 0; j < 16; ++j) tl[j] = NEG_INF;
    for (int i = t; i < NT2 * 16; i += 256) {
        float v = pr[i];
        if (v > tl[15]) {
            tl[15] = v;
#pragma unroll
            for (int j = 15; j > 0; --j) {
                float a = tl[j - 1], bb = tl[j];
                if (bb > a) { tl[j - 1] = bb; tl[j] = a; }
            }
        }
    }

    __shared__ float vals[256 * 16];
    __shared__ float red_v[256];
    __shared__ int red_i[256];
    __shared__ float found[16];
#pragma unroll
    for (int j = 0; j < 16; ++j) vals[t * 16 + j] = tl[j];
    __syncthreads();

    for (int it = 0; it < 16; ++it) {
        float mv = NEG_INF; int mi = t * 16;
#pragma unroll
        for (int j = 0; j < 16; ++j) {
            float v = vals[t * 16 + j];
            if (v > mv) { mv = v; mi = t * 16 + j; }
        }
        red_v[t] = mv; red_i[t] = mi;
        __syncthreads();
        for (int s = 128; s; s >>= 1) {
            if (t < s) {
                if (red_v[t + s] > red_v[t]) { red_v[t] = red_v[t + s]; red_i[t] = red_i[t + s]; }
            }
            __syncthreads();
        }
        if (t == 0) { found[it] = red_v[0]; vals[red_i[0]] = NEG_INF; }
        __syncthreads();
    }

    // pos = dot(q_hat[b], out_eb[lab]) * inv_norm[lab] / TEMP  (fp32)
    int lab = labels[b];
    const float* qr = q_hat + ((long)b << 9);
    const float* er = out_eb + ((long)lab << 9);
    red_v[t] = qr[t] * er[t] + qr[t + 256] * er[t + 256];
    __syncthreads();
    for (int s = 128; s; s >>= 1) {
        if (t < s) red_v[t] += red_v[t + s];
        __syncthreads();
    }
    if (t == 0) {
        float pos = red_v[0] * inv_norm[lab] * INV_TEMP;
        float mx = fmaxf(pos, found[0]);
        float s = expf(pos - mx);
#pragma unroll
        for (int j = 0; j < 16; ++j) s += expf(found[j] - mx);
        lnce[b] = logf(s) + mx - pos;
    }
}

// --------------------------------------------------------------- align loss partial
__global__ void align_kernel(const float* __restrict__ q_hat, const float* __restrict__ sat,
                             const float* __restrict__ out_eb, const float* __restrict__ inv_norm,
                             const int* __restrict__ labels, float* __restrict__ lalign) {
    int b = blockIdx.x;
    int lane = threadIdx.x;  // 64
    int lab = labels[b];
    const float4* dq = (const float4*)(q_hat + (long)b * DE);
    const float4* sr = (const float4*)(sat + (long)b * DE);
    const float4* er = (const float4*)(out_eb + (long)lab * DE);
    float dot_dp = 0.f, dot_sp = 0.f, ss_s = 0.f;
#pragma unroll
    for (int rr = 0; rr < 2; ++rr) {
        int j = lane + rr * 64;
        float4 d4 = dq[j], s4 = sr[j], e4 = er[j];
        dot_dp += d4.x * e4.x + d4.y * e4.y + d4.z * e4.z + d4.w * e4.w;
        dot_sp += s4.x * e4.x + s4.y * e4.y + s4.z * e4.z + s4.w * e4.w;
        ss_s += s4.x * s4.x + s4.y * s4.y + s4.z * s4.z + s4.w * s4.w;
    }
#pragma unroll
    for (int off = 32; off; off >>= 1) {
        dot_dp += __shfl_xor(dot_dp, off);
        dot_sp += __shfl_xor(dot_sp, off);
        ss_s += __shfl_xor(ss_s, off);
    }
    if (lane == 0) {
        float invl = inv_norm[lab];
        float pd = dot_dp * invl;
        float ps = dot_sp * invl / fmaxf(sqrtf(ss_s), 1e-12f);
        lalign[b] = 1.0f - 0.5f * (pd + ps);
    }
}

// ------------------------------------------------------------------- finalize means
__global__ void finalize(const float* __restrict__ lnce, const float* __restrict__ lalign,
                         float* __restrict__ out_losses) {
    __shared__ float s1[256], s2[256];
    int t = threadIdx.x;
    s1[t] = lnce[t] + lnce[t + 256];
    s2[t] = lalign[t] + lalign[t + 256];
    __syncthreads();
    for (int s = 128; s; s >>= 1) {
        if (t < s) { s1[t] += s1[t + s]; s2[t] += s2[t + s]; }
        __syncthreads();
    }
    if (t == 0) {
        out_losses[0] = s1[0] / (float)B_SZ;
        out_losses[1] = s2[0] / (float)B_SZ;
    }
}

extern "C" void kernel_launch(void* const* d_in, const int* in_sizes, int n_in,
                              void* d_out, int out_size, void* d_ws, size_t ws_size,
                              hipStream_t stream) {
    const float* pf = (const float*)d_in[0];
    const float* emb = (const float*)d_in[1];
    const float* sat = (const float*)d_in[2];
    const float* pb = (const float*)d_in[3];
    const float* ebank = (const float*)d_in[4];
    const int* labels = (const int*)d_in[5];

    float* out = (float*)d_out;
    float* out_pb = out;
    float* out_eb = out + PART_BANK_N;
    float* out_losses = out + PART_BANK_N + EMB_BANK_N;

    // ws layout (floats):
    // q_hat 262,144 | inv_norm 20,000 | inv_map 20,000(int) | lnce 512 | lalign 512
    // | partials 512*314*16 = 2,571,264 | Ab u16 262,144 | Bb u16 10,240,000
    float* ws = (float*)d_ws;
    float* q_hat = ws;
    float* inv_norm = q_hat + (long)B_SZ * DE;
    int* inv_map = (int*)(inv_norm + C_CLASSES);
    float* lnce = (float*)(inv_map + C_CLASSES);
    float* lalign = lnce + B_SZ;
    float* partials = lalign + B_SZ;
    unsigned short* Ab = (unsigned short*)(partials + (long)B_SZ * NT2 * 16);
    unsigned short* Bb = Ab + (long)B_SZ * DE;

    hipMemsetAsync(inv_map, 0xFF, C_CLASSES * sizeof(int), stream);  // -1
    qnorm_conv<<<B_SZ, 64, 0, stream>>>(emb, labels, q_hat, Ab, inv_map);
    embed_pass<<<C_CLASSES / 4, 256, 0, stream>>>(ebank, emb, inv_map, out_eb, Bb, inv_norm);
    part_pass<<<C_CLASSES, 256, 0, stream>>>((const float4*)pb, (const float4*)pf, inv_map,
                                             (float4*)out_pb);

    dim3 grid(4, NTILE);  // bm x bn
    gemm_topk<<<grid, 256, 0, stream>>>(Ab, Bb, inv_norm, labels, partials);

    merge_nce<<<B_SZ, 256, 0, stream>>>(partials, q_hat, out_eb, inv_norm, labels, lnce);
    align_kernel<<<B_SZ, 64, 0, stream>>>(q_hat, sat, out_eb, inv_norm, labels, lalign);
    finalize<<<1, 256, 0, stream>>>(lnce, lalign, out_losses);
}

// Round 4
// 178.240 us; speedup vs baseline: 1.1110x; 1.1110x over previous
//
#include <hip/hip_runtime.h>
#include <math.h>

#define MOM 0.999f
#define ONE_M_MOM 0.001f
#define INV_TEMP (1.0f / 0.07f)
#define C_CLASSES 20000
#define B_SZ 512
#define DE 512
#define PART_ROW 2048                       // K * Dp = 8 * 256
#define PART_BANK_N (C_CLASSES * PART_ROW)  // 40,960,000 floats
#define EMB_BANK_N (C_CLASSES * DE)         // 10,240,000 floats
#define NEG_INF (-3.0e38f)
#define NTILE 157         // ceil(20000/128)
#define NT2 (NTILE * 2)   // 314 half-tiles per row

typedef __attribute__((ext_vector_type(8))) short short8;
typedef __attribute__((ext_vector_type(4))) float f32x4;

__device__ inline unsigned short f2bf_rne(float f) {
    unsigned u = __builtin_bit_cast(unsigned, f);
    return (unsigned short)((u + 0x7FFFu + ((u >> 16) & 1u)) >> 16);
}

__device__ inline float bf2f(unsigned short u) {
    return __builtin_bit_cast(float, (unsigned)u << 16);
}

__device__ inline void gload16(const void* g, void* l) {
    __builtin_amdgcn_global_load_lds(
        (const __attribute__((address_space(1))) unsigned int*)g,
        (__attribute__((address_space(3))) unsigned int*)l, 16, 0, 0);
}

// --------- inv_map[c] = batch index with label c, else -1 (replaces memset+scatter)
__global__ void build_map(const int* __restrict__ labels, int* __restrict__ inv_map) {
    __shared__ int lab[B_SZ];
    int t = threadIdx.x;  // 256
    lab[t] = labels[t];
    lab[t + 256] = labels[t + 256];
    __syncthreads();
    int c = blockIdx.x * 256 + t;
    if (c >= C_CLASSES) return;
    int m = -1;
    for (int i = 0; i < B_SZ; ++i)
        if (lab[i] == c) m = i;
    inv_map[c] = m;
}

// --------- normalize embeddings -> q_hat fp32 + A bf16
__global__ void qnorm_conv(const float* __restrict__ emb, float* __restrict__ q_hat,
                           unsigned short* __restrict__ Ab) {
    int b = blockIdx.x;
    int l = threadIdx.x;  // 64
    const float4* row = (const float4*)(emb + (long)b * DE);
    float4 v0 = row[2 * l], v1 = row[2 * l + 1];
    float ss = v0.x * v0.x + v0.y * v0.y + v0.z * v0.z + v0.w * v0.w
             + v1.x * v1.x + v1.y * v1.y + v1.z * v1.z + v1.w * v1.w;
#pragma unroll
    for (int off = 32; off; off >>= 1) ss += __shfl_xor(ss, off);
    float inv = 1.0f / fmaxf(sqrtf(ss), 1e-12f);
    v0.x *= inv; v0.y *= inv; v0.z *= inv; v0.w *= inv;
    v1.x *= inv; v1.y *= inv; v1.z *= inv; v1.w *= inv;
    float4* out = (float4*)(q_hat + (long)b * DE);
    out[2 * l] = v0; out[2 * l + 1] = v1;
    short8 o;
    o[0] = (short)f2bf_rne(v0.x); o[1] = (short)f2bf_rne(v0.y);
    o[2] = (short)f2bf_rne(v0.z); o[3] = (short)f2bf_rne(v0.w);
    o[4] = (short)f2bf_rne(v1.x); o[5] = (short)f2bf_rne(v1.y);
    o[6] = (short)f2bf_rne(v1.z); o[7] = (short)f2bf_rne(v1.w);
    *(short8*)(Ab + (long)b * DE + l * 8) = o;
}

// --------- part bank: single-pass copy + EMA (row-labeled)
__global__ void part_pass(const float4* __restrict__ pb, const float4* __restrict__ pf,
                          const int* __restrict__ inv_map, float4* __restrict__ out_pb) {
    int c = blockIdx.x;   // 20000
    int t = threadIdx.x;  // 256
    long base = (long)c * (PART_ROW / 4);
    int mb = inv_map[c];
    if (mb >= 0) {
        const float4* src = pf + (long)mb * (PART_ROW / 4);
#pragma unroll
        for (int it = 0; it < 2; ++it) {
            int j = t + it * 256;
            float4 o = pb[base + j], n = src[j], r;
            r.x = MOM * o.x + ONE_M_MOM * n.x;
            r.y = MOM * o.y + ONE_M_MOM * n.y;
            r.z = MOM * o.z + ONE_M_MOM * n.z;
            r.w = MOM * o.w + ONE_M_MOM * n.w;
            out_pb[base + j] = r;
        }
    } else {
#pragma unroll
        for (int it = 0; it < 2; ++it) {
            int j = t + it * 256;
            out_pb[base + j] = pb[base + j];
        }
    }
}

// --------- embed bank: copy + EMA + row norm + bf16, single pass
__global__ void embed_pass(const float* __restrict__ ebank, const float* __restrict__ emb,
                           const int* __restrict__ inv_map, float* __restrict__ out_eb,
                           unsigned short* __restrict__ Bb, float* __restrict__ inv_norm) {
    int w = threadIdx.x >> 6, l = threadIdx.x & 63;
    int c = blockIdx.x * 4 + w;  // < 20000
    const float4* row = (const float4*)(ebank + ((long)c << 9));
    float4 v0 = row[2 * l], v1 = row[2 * l + 1];
    int mb = inv_map[c];
    if (mb >= 0) {
        const float4* nr = (const float4*)(emb + ((long)mb << 9));
        float4 n0 = nr[2 * l], n1 = nr[2 * l + 1];
        v0.x = MOM * v0.x + ONE_M_MOM * n0.x;
        v0.y = MOM * v0.y + ONE_M_MOM * n0.y;
        v0.z = MOM * v0.z + ONE_M_MOM * n0.z;
        v0.w = MOM * v0.w + ONE_M_MOM * n0.w;
        v1.x = MOM * v1.x + ONE_M_MOM * n1.x;
        v1.y = MOM * v1.y + ONE_M_MOM * n1.y;
        v1.z = MOM * v1.z + ONE_M_MOM * n1.z;
        v1.w = MOM * v1.w + ONE_M_MOM * n1.w;
    }
    float4* orow = (float4*)(out_eb + ((long)c << 9));
    orow[2 * l] = v0; orow[2 * l + 1] = v1;
    float ss = v0.x * v0.x + v0.y * v0.y + v0.z * v0.z + v0.w * v0.w
             + v1.x * v1.x + v1.y * v1.y + v1.z * v1.z + v1.w * v1.w;
#pragma unroll
    for (int off = 32; off; off >>= 1) ss += __shfl_xor(ss, off);
    if (l == 0) inv_norm[c] = 1.0f / fmaxf(sqrtf(ss), 1e-12f);
    short8 o;
    o[0] = (short)f2bf_rne(v0.x); o[1] = (short)f2bf_rne(v0.y);
    o[2] = (short)f2bf_rne(v0.z); o[3] = (short)f2bf_rne(v0.w);
    o[4] = (short)f2bf_rne(v1.x); o[5] = (short)f2bf_rne(v1.y);
    o[6] = (short)f2bf_rne(v1.z); o[7] = (short)f2bf_rne(v1.w);
    *(short8*)(Bb + ((long)c << 9) + l * 8) = o;
}

// --------- MFMA GEMM + fused per-tile top-16 partials
// A bf16 [512][512], B bf16 [20000][512]. Tile 128x128, BK=64, 4 waves.
// LDS: XOR-swizzled (slot ^= row&7) staging, written via pre-swizzled global src
// (global_load_lds writes linearly — rule #21). Epilogue stile in bf16 (union).
__global__ void __launch_bounds__(256)
gemm_topk(const unsigned short* __restrict__ A, const unsigned short* __restrict__ B,
          const float* __restrict__ inv_norm, const int* __restrict__ labels,
          float* __restrict__ partials) {
    __shared__ unsigned short smem[128 * 130];  // 33,280 B
    unsigned short* Asm = smem;          // 128 rows x 64 k = 16 KB
    unsigned short* Bsm = smem + 8192;   // 16 KB

    const int t = threadIdx.x;
    const int w = t >> 6, l = t & 63;
    const int wr = w >> 1, wc = w & 1;

    // bijective XCD-chunked remap of 628 blocks (8 XCDs; q=78, r=4)
    int id = blockIdx.x;
    int xcd = id & 7, idx = id >> 3;
    int wg = (xcd < 4) ? xcd * 79 + idx : 316 + (xcd - 4) * 78 + idx;
    const int bm = wg & 3, bn = wg >> 2;

    f32x4 acc[4][4] = {};

    // staging: thread t -> dest row (chunk*32 + t/8), slot t&7 (16B units)
    // source k-chunk pre-swizzled: c_src = (t&7) ^ (dest_row & 7)
    const int srow = t >> 3;                           // 0..31
    const long swz = ((t & 7) ^ (srow & 7)) << 3;      // element offset
    const unsigned short* Ag = A + ((long)(bm * 128 + srow) << 9) + swz;
    const unsigned short* Bg[4];
#pragma unroll
    for (int i = 0; i < 4; ++i) {
        int br = bn * 128 + i * 32 + srow;
        if (br > C_CLASSES - 1) br = C_CLASSES - 1;
        Bg[i] = B + ((long)br << 9) + swz;
    }
    char* Adst = (char*)Asm + (w << 10);
    char* Bdst = (char*)Bsm + (w << 10);

    const int fr = l & 15;
    const int s4 = l >> 4;  // 0..3
    // frag read byte offsets for k-halves kk=0,1 (swizzled)
    const int swr0 = ((s4) ^ (fr & 7)) << 4;
    const int swr1 = ((4 + s4) ^ (fr & 7)) << 4;

    for (int kt = 0; kt < 8; ++kt) {
        const int ko = kt << 6;
#pragma unroll
        for (int i = 0; i < 4; ++i) {
            gload16(Ag + ko + ((long)i << 14), Adst + (i << 12));
            gload16(Bg[i] + ko, Bdst + (i << 12));
        }
        __syncthreads();
        short8 af[2][4], bf[2][4];
        const char* Abase = (const char*)Asm;
        const char* Bbase = (const char*)Bsm;
#pragma unroll
        for (int m = 0; m < 4; ++m) {
            int ra = (wr * 64 + m * 16 + fr) << 7;
            int rb = (wc * 64 + m * 16 + fr) << 7;
            af[0][m] = *(const short8*)(Abase + ra + swr0);
            af[1][m] = *(const short8*)(Abase + ra + swr1);
            bf[0][m] = *(const short8*)(Bbase + rb + swr0);
            bf[1][m] = *(const short8*)(Bbase + rb + swr1);
        }
#pragma unroll
        for (int kk = 0; kk < 2; ++kk)
#pragma unroll
            for (int m = 0; m < 4; ++m)
#pragma unroll
                for (int n = 0; n < 4; ++n)
                    acc[m][n] = __builtin_amdgcn_mfma_f32_16x16x32_bf16(
                        af[kk][m], bf[kk][n], acc[m][n], 0, 0, 0);
        __syncthreads();
    }

    // ---- dump scaled sim into bf16 stile (C/D: col=lane&15, row=(lane>>4)*4+j)
    unsigned short* stile = smem;  // [128][130] bf16, overlays staging
    const int r4 = s4 << 2;
#pragma unroll
    for (int n = 0; n < 4; ++n) {
        int ct = wc * 64 + fr + n * 16;
        int cg = bn * 128 + ct;
        bool ok = cg < C_CLASSES;
        float sc = ok ? inv_norm[cg] * INV_TEMP : 0.0f;
#pragma unroll
        for (int m = 0; m < 4; ++m) {
            int rt = wr * 64 + r4 + m * 16;
#pragma unroll
            for (int j = 0; j < 4; ++j) {
                float v = ok ? acc[m][n][j] * sc : NEG_INF;
                stile[(rt + j) * 130 + ct] = f2bf_rne(v);
            }
        }
    }
    __syncthreads();

    // ---- per-row half-tile top-16
    const int r = t >> 1, half = t & 1;
    const int gr = bm * 128 + r;          // < 512 always
    const int lab = labels[gr];
    const int lab_l = lab - (bn << 7) - (half << 6);
    const unsigned short* bp = stile + r * 130 + half * 64;
    float tl[16];
#pragma unroll
    for (int j = 0; j < 16; ++j) tl[j] = NEG_INF;
    for (int c = 0; c < 64; ++c) {
        if (c == lab_l) continue;
        float v = bf2f(bp[c]);
        if (v > tl[15]) {
            tl[15] = v;
#pragma unroll
            for (int j = 15; j > 0; --j) {
                float a = tl[j - 1], bb = tl[j];
                if (bb > a) { tl[j - 1] = bb; tl[j] = a; }
            }
        }
    }
    float* op = partials + ((long)gr * NT2 + (bn << 1) + half) * 16;
#pragma unroll
    for (int j = 0; j < 16; ++j) op[j] = tl[j];
}

// --------- merge partials -> top-16; pos via fp32 dot; logsumexp; + align loss
__global__ void merge_nce_align(const float* __restrict__ partials,
                                const float* __restrict__ q_hat,
                                const float* __restrict__ out_eb,
                                const float* __restrict__ sat,
                                const float* __restrict__ inv_norm,
                                const int* __restrict__ labels,
                                float* __restrict__ lnce, float* __restrict__ lalign) {
    int b = blockIdx.x;
    int t = threadIdx.x;  // 256
    const float* pr = partials + (long)b * (NT2 * 16);

    float tl[16];
#pragma unroll
    for (int j = 0; j < 16; ++j) tl[j] = NEG_INF;
    for (int i = t; i < NT2 * 16; i += 256) {
        float v = pr[i];
        if (v > tl[15]) {
            tl[15] = v;
#pragma unroll
            for (int j = 15; j > 0; --j) {
                float a = tl[j - 1], bb = tl[j];
                if (bb > a) { tl[j - 1] = bb; tl[j] = a; }
            }
        }
    }

    __shared__ float vals[256 * 16];
    __shared__ float red_v[256];
    __shared__ int red_i[256];
    __shared__ float found[16];
#pragma unroll
    for (int j = 0; j < 16; ++j) vals[t * 16 + j] = tl[j];
    __syncthreads();

    for (int it = 0; it < 16; ++it) {
        float mv = NEG_INF; int mi = t * 16;
#pragma unroll
        for (int j = 0; j < 16; ++j) {
            float v = vals[t * 16 + j];
            if (v > mv) { mv = v; mi = t * 16 + j; }
        }
        red_v[t] = mv; red_i[t] = mi;
        __syncthreads();
        for (int s = 128; s; s >>= 1) {
            if (t < s) {
                if (red_v[t + s] > red_v[t]) { red_v[t] = red_v[t + s]; red_i[t] = red_i[t + s]; }
            }
            __syncthreads();
        }
        if (t == 0) { found[it] = red_v[0]; vals[red_i[0]] = NEG_INF; }
        __syncthreads();
    }

    // three dots: q.e, s.e, s.s (fp32)
    int lab = labels[b];
    const float* qr = q_hat + ((long)b << 9);
    const float* er = out_eb + ((long)lab << 9);
    const float* sr = sat + ((long)b << 9);
    float a1 = qr[t] * er[t] + qr[t + 256] * er[t + 256];
    float a2 = sr[t] * er[t] + sr[t + 256] * er[t + 256];
    float a3 = sr[t] * sr[t] + sr[t + 256] * sr[t + 256];
    red_v[t] = a1; vals[t] = a2; vals[256 + t] = a3;
    __syncthreads();
    for (int s = 128; s; s >>= 1) {
        if (t < s) {
            red_v[t] += red_v[t + s];
            vals[t] += vals[t + s];
            vals[256 + t] += vals[256 + t + s];
        }
        __syncthreads();
    }
    if (t == 0) {
        float invl = inv_norm[lab];
        float dot_qe = red_v[0], dot_se = vals[0], ss_s = vals[256];
        float pos = dot_qe * invl * INV_TEMP;
        float mx = fmaxf(pos, found[0]);
        float ssum = expf(pos - mx);
#pragma unroll
        for (int j = 0; j < 16; ++j) ssum += expf(found[j] - mx);
        lnce[b] = logf(ssum) + mx - pos;
        float pd = dot_qe * invl;
        float ps = dot_se * invl / fmaxf(sqrtf(ss_s), 1e-12f);
        lalign[b] = 1.0f - 0.5f * (pd + ps);
    }
}

// ------------------------------------------------------------------- finalize means
__global__ void finalize(const float* __restrict__ lnce, const float* __restrict__ lalign,
                         float* __restrict__ out_losses) {
    __shared__ float s1[256], s2[256];
    int t = threadIdx.x;
    s1[t] = lnce[t] + lnce[t + 256];
    s2[t] = lalign[t] + lalign[t + 256];
    __syncthreads();
    for (int s = 128; s; s >>= 1) {
        if (t < s) { s1[t] += s1[t + s]; s2[t] += s2[t + s]; }
        __syncthreads();
    }
    if (t == 0) {
        out_losses[0] = s1[0] / (float)B_SZ;
        out_losses[1] = s2[0] / (float)B_SZ;
    }
}

extern "C" void kernel_launch(void* const* d_in, const int* in_sizes, int n_in,
                              void* d_out, int out_size, void* d_ws, size_t ws_size,
                              hipStream_t stream) {
    const float* pf = (const float*)d_in[0];
    const float* emb = (const float*)d_in[1];
    const float* sat = (const float*)d_in[2];
    const float* pb = (const float*)d_in[3];
    const float* ebank = (const float*)d_in[4];
    const int* labels = (const int*)d_in[5];

    float* out = (float*)d_out;
    float* out_pb = out;
    float* out_eb = out + PART_BANK_N;
    float* out_losses = out + PART_BANK_N + EMB_BANK_N;

    // ws layout (floats):
    // q_hat 262,144 | inv_norm 20,000 | inv_map 20,000(int) | lnce 512 | lalign 512
    // | partials 512*314*16 | Ab u16 262,144 | Bb u16 10,240,000   (~33 MB total)
    float* ws = (float*)d_ws;
    float* q_hat = ws;
    float* inv_norm = q_hat + (long)B_SZ * DE;
    int* inv_map = (int*)(inv_norm + C_CLASSES);
    float* lnce = (float*)(inv_map + C_CLASSES);
    float* lalign = lnce + B_SZ;
    float* partials = lalign + B_SZ;
    unsigned short* Ab = (unsigned short*)(partials + (long)B_SZ * NT2 * 16);
    unsigned short* Bb = Ab + (long)B_SZ * DE;

    build_map<<<(C_CLASSES + 255) / 256, 256, 0, stream>>>(labels, inv_map);
    qnorm_conv<<<B_SZ, 64, 0, stream>>>(emb, q_hat, Ab);
    embed_pass<<<C_CLASSES / 4, 256, 0, stream>>>(ebank, emb, inv_map, out_eb, Bb, inv_norm);
    part_pass<<<C_CLASSES, 256, 0, stream>>>((const float4*)pb, (const float4*)pf, inv_map,
                                             (float4*)out_pb);

    gemm_topk<<<4 * NTILE, 256, 0, stream>>>(Ab, Bb, inv_norm, labels, partials);

    merge_nce_align<<<B_SZ, 256, 0, stream>>>(partials, q_hat, out_eb, sat, inv_norm,
                                              labels, lnce, lalign);
    finalize<<<1, 256, 0, stream>>>(lnce, lalign, out_losses);
}

// Round 5
// 159.994 us; speedup vs baseline: 1.2377x; 1.1140x over previous
//
#include <hip/hip_runtime.h>
#include <math.h>

#define MOM 0.999f
#define ONE_M_MOM 0.001f
#define INV_TEMP (1.0f / 0.07f)
#define C_CLASSES 20000
#define B_SZ 512
#define DE 512
#define PART_ROW 2048                       // K * Dp = 8 * 256
#define PART_BANK_N (C_CLASSES * PART_ROW)  // 40,960,000 floats
#define EMB_BANK_N (C_CLASSES * DE)         // 10,240,000 floats
#define NEG_INF (-3.0e38f)
#define NTILE 157         // ceil(20000/128)
#define NT2 (NTILE * 2)   // 314 half-tiles per row
#define NGEMM (4 * NTILE) // 628 gemm blocks

typedef __attribute__((ext_vector_type(8))) short short8;
typedef __attribute__((ext_vector_type(4))) float f32x4;

__device__ inline unsigned short f2bf_rne(float f) {
    unsigned u = __builtin_bit_cast(unsigned, f);
    return (unsigned short)((u + 0x7FFFu + ((u >> 16) & 1u)) >> 16);
}

__device__ inline float bf2f(unsigned short u) {
    return __builtin_bit_cast(float, (unsigned)u << 16);
}

__device__ inline void gload16(const void* g, void* l) {
    __builtin_amdgcn_global_load_lds(
        (const __attribute__((address_space(1))) unsigned int*)g,
        (__attribute__((address_space(3))) unsigned int*)l, 16, 0, 0);
}

// --------- inv_map[c] = batch index with label c, else -1
__global__ void build_map(const int* __restrict__ labels, int* __restrict__ inv_map) {
    __shared__ int lab[B_SZ];
    int t = threadIdx.x;  // 256
    lab[t] = labels[t];
    lab[t + 256] = labels[t + 256];
    __syncthreads();
    int c = blockIdx.x * 256 + t;
    if (c >= C_CLASSES) return;
    int m = -1;
    for (int i = 0; i < B_SZ; ++i)
        if (lab[i] == c) m = i;
    inv_map[c] = m;
}

// --------- blocks 0..4999: embed bank copy+EMA+norm+bf16; 5000..5127: qnorm+conv
__global__ void embed_qnorm(const float* __restrict__ ebank, const float* __restrict__ emb,
                            const int* __restrict__ inv_map, float* __restrict__ out_eb,
                            unsigned short* __restrict__ Bb, float* __restrict__ inv_norm,
                            float* __restrict__ q_hat, unsigned short* __restrict__ Ab) {
    int w = threadIdx.x >> 6, l = threadIdx.x & 63;
    int blk = blockIdx.x;
    if (blk < 5000) {
        int c = blk * 4 + w;  // < 20000
        const float4* row = (const float4*)(ebank + ((long)c << 9));
        float4 v0 = row[2 * l], v1 = row[2 * l + 1];
        int mb = inv_map[c];
        if (mb >= 0) {
            const float4* nr = (const float4*)(emb + ((long)mb << 9));
            float4 n0 = nr[2 * l], n1 = nr[2 * l + 1];
            v0.x = MOM * v0.x + ONE_M_MOM * n0.x;
            v0.y = MOM * v0.y + ONE_M_MOM * n0.y;
            v0.z = MOM * v0.z + ONE_M_MOM * n0.z;
            v0.w = MOM * v0.w + ONE_M_MOM * n0.w;
            v1.x = MOM * v1.x + ONE_M_MOM * n1.x;
            v1.y = MOM * v1.y + ONE_M_MOM * n1.y;
            v1.z = MOM * v1.z + ONE_M_MOM * n1.z;
            v1.w = MOM * v1.w + ONE_M_MOM * n1.w;
        }
        float4* orow = (float4*)(out_eb + ((long)c << 9));
        orow[2 * l] = v0; orow[2 * l + 1] = v1;
        float ss = v0.x * v0.x + v0.y * v0.y + v0.z * v0.z + v0.w * v0.w
                 + v1.x * v1.x + v1.y * v1.y + v1.z * v1.z + v1.w * v1.w;
#pragma unroll
        for (int off = 32; off; off >>= 1) ss += __shfl_xor(ss, off);
        if (l == 0) inv_norm[c] = 1.0f / fmaxf(sqrtf(ss), 1e-12f);
        short8 o;
        o[0] = (short)f2bf_rne(v0.x); o[1] = (short)f2bf_rne(v0.y);
        o[2] = (short)f2bf_rne(v0.z); o[3] = (short)f2bf_rne(v0.w);
        o[4] = (short)f2bf_rne(v1.x); o[5] = (short)f2bf_rne(v1.y);
        o[6] = (short)f2bf_rne(v1.z); o[7] = (short)f2bf_rne(v1.w);
        *(short8*)(Bb + ((long)c << 9) + l * 8) = o;
    } else {
        int b = (blk - 5000) * 4 + w;  // < 512
        const float4* row = (const float4*)(emb + ((long)b << 9));
        float4 v0 = row[2 * l], v1 = row[2 * l + 1];
        float ss = v0.x * v0.x + v0.y * v0.y + v0.z * v0.z + v0.w * v0.w
                 + v1.x * v1.x + v1.y * v1.y + v1.z * v1.z + v1.w * v1.w;
#pragma unroll
        for (int off = 32; off; off >>= 1) ss += __shfl_xor(ss, off);
        float inv = 1.0f / fmaxf(sqrtf(ss), 1e-12f);
        v0.x *= inv; v0.y *= inv; v0.z *= inv; v0.w *= inv;
        v1.x *= inv; v1.y *= inv; v1.z *= inv; v1.w *= inv;
        float4* outq = (float4*)(q_hat + ((long)b << 9));
        outq[2 * l] = v0; outq[2 * l + 1] = v1;
        short8 o;
        o[0] = (short)f2bf_rne(v0.x); o[1] = (short)f2bf_rne(v0.y);
        o[2] = (short)f2bf_rne(v0.z); o[3] = (short)f2bf_rne(v0.w);
        o[4] = (short)f2bf_rne(v1.x); o[5] = (short)f2bf_rne(v1.y);
        o[6] = (short)f2bf_rne(v1.z); o[7] = (short)f2bf_rne(v1.w);
        *(short8*)(Ab + ((long)b << 9) + l * 8) = o;
    }
}

// --------- fused: blocks [0,628) MFMA GEMM + top-16 partials; [628, 20628) part bank
__global__ void __launch_bounds__(256)
part_gemm(const unsigned short* __restrict__ A, const unsigned short* __restrict__ B,
          const float* __restrict__ inv_norm, const int* __restrict__ labels,
          float* __restrict__ partials,
          const float4* __restrict__ pb, const float4* __restrict__ pf,
          const int* __restrict__ inv_map, float4* __restrict__ out_pb) {
    if (blockIdx.x >= NGEMM) {
        // ---------------- part bank row copy / EMA ----------------
        int c = blockIdx.x - NGEMM;   // 0..19999
        int t = threadIdx.x;          // 256
        long base = (long)c * (PART_ROW / 4);
        int mb = inv_map[c];
        if (mb >= 0) {
            const float4* src = pf + (long)mb * (PART_ROW / 4);
#pragma unroll
            for (int it = 0; it < 2; ++it) {
                int j = t + it * 256;
                float4 o = pb[base + j], n = src[j], r;
                r.x = MOM * o.x + ONE_M_MOM * n.x;
                r.y = MOM * o.y + ONE_M_MOM * n.y;
                r.z = MOM * o.z + ONE_M_MOM * n.z;
                r.w = MOM * o.w + ONE_M_MOM * n.w;
                out_pb[base + j] = r;
            }
        } else {
#pragma unroll
            for (int it = 0; it < 2; ++it) {
                int j = t + it * 256;
                out_pb[base + j] = pb[base + j];
            }
        }
        return;
    }

    // ---------------- GEMM tile + fused top-16 ----------------
    __shared__ unsigned short smem[128 * 130];  // 33,280 B
    unsigned short* Asm = smem;          // 128 rows x 64 k = 16 KB
    unsigned short* Bsm = smem + 8192;   // 16 KB

    const int t = threadIdx.x;
    const int w = t >> 6, l = t & 63;
    const int wr = w >> 1, wc = w & 1;

    // bijective XCD-chunked remap of 628 gemm blocks (8 XCDs; q=78, r=4)
    int id = blockIdx.x;
    int xcd = id & 7, idx = id >> 3;
    int wg = (xcd < 4) ? xcd * 79 + idx : 316 + (xcd - 4) * 78 + idx;
    const int bm = wg & 3, bn = wg >> 2;

    f32x4 acc[4][4] = {};

    const int srow = t >> 3;                           // 0..31
    const long swz = ((t & 7) ^ (srow & 7)) << 3;      // pre-swizzled source offset
    const unsigned short* Ag = A + ((long)(bm * 128 + srow) << 9) + swz;
    const unsigned short* Bg[4];
#pragma unroll
    for (int i = 0; i < 4; ++i) {
        int br = bn * 128 + i * 32 + srow;
        if (br > C_CLASSES - 1) br = C_CLASSES - 1;
        Bg[i] = B + ((long)br << 9) + swz;
    }
    char* Adst = (char*)Asm + (w << 10);
    char* Bdst = (char*)Bsm + (w << 10);

    const int fr = l & 15;
    const int s4 = l >> 4;  // 0..3
    const int swr0 = ((s4) ^ (fr & 7)) << 4;
    const int swr1 = ((4 + s4) ^ (fr & 7)) << 4;

    for (int kt = 0; kt < 8; ++kt) {
        const int ko = kt << 6;
#pragma unroll
        for (int i = 0; i < 4; ++i) {
            gload16(Ag + ko + ((long)i << 14), Adst + (i << 12));
            gload16(Bg[i] + ko, Bdst + (i << 12));
        }
        __syncthreads();
        short8 af[2][4], bf[2][4];
        const char* Abase = (const char*)Asm;
        const char* Bbase = (const char*)Bsm;
#pragma unroll
        for (int m = 0; m < 4; ++m) {
            int ra = (wr * 64 + m * 16 + fr) << 7;
            int rb = (wc * 64 + m * 16 + fr) << 7;
            af[0][m] = *(const short8*)(Abase + ra + swr0);
            af[1][m] = *(const short8*)(Abase + ra + swr1);
            bf[0][m] = *(const short8*)(Bbase + rb + swr0);
            bf[1][m] = *(const short8*)(Bbase + rb + swr1);
        }
#pragma unroll
        for (int kk = 0; kk < 2; ++kk)
#pragma unroll
            for (int m = 0; m < 4; ++m)
#pragma unroll
                for (int n = 0; n < 4; ++n)
                    acc[m][n] = __builtin_amdgcn_mfma_f32_16x16x32_bf16(
                        af[kk][m], bf[kk][n], acc[m][n], 0, 0, 0);
        __syncthreads();
    }

    // ---- dump scaled sim into bf16 stile (C/D: col=lane&15, row=(lane>>4)*4+j)
    unsigned short* stile = smem;  // [128][130] bf16
    const int r4 = s4 << 2;
#pragma unroll
    for (int n = 0; n < 4; ++n) {
        int ct = wc * 64 + fr + n * 16;
        int cg = bn * 128 + ct;
        bool ok = cg < C_CLASSES;
        float sc = ok ? inv_norm[cg] * INV_TEMP : 0.0f;
#pragma unroll
        for (int m = 0; m < 4; ++m) {
            int rt = wr * 64 + r4 + m * 16;
#pragma unroll
            for (int j = 0; j < 4; ++j) {
                float v = ok ? acc[m][n][j] * sc : NEG_INF;
                stile[(rt + j) * 130 + ct] = f2bf_rne(v);
            }
        }
    }
    __syncthreads();

    // ---- per-row half-tile top-16
    const int r = t >> 1, half = t & 1;
    const int gr = bm * 128 + r;
    const int lab = labels[gr];
    const int lab_l = lab - (bn << 7) - (half << 6);
    const unsigned short* bp = stile + r * 130 + half * 64;
    float tl[16];
#pragma unroll
    for (int j = 0; j < 16; ++j) tl[j] = NEG_INF;
    for (int c = 0; c < 64; ++c) {
        if (c == lab_l) continue;
        float v = bf2f(bp[c]);
        if (v > tl[15]) {
            tl[15] = v;
#pragma unroll
            for (int j = 15; j > 0; --j) {
                float a = tl[j - 1], bb = tl[j];
                if (bb > a) { tl[j - 1] = bb; tl[j] = a; }
            }
        }
    }
    float* op = partials + ((long)gr * NT2 + (bn << 1) + half) * 16;
#pragma unroll
    for (int j = 0; j < 16; ++j) op[j] = tl[j];
}

// --------- one wave per row: merge partials top-16, logsumexp, align loss
__global__ void merge_nce_align(const float* __restrict__ partials,
                                const float* __restrict__ q_hat,
                                const float* __restrict__ out_eb,
                                const float* __restrict__ sat,
                                const float* __restrict__ inv_norm,
                                const int* __restrict__ labels,
                                float* __restrict__ lnce, float* __restrict__ lalign) {
    int b = blockIdx.x;
    int l = threadIdx.x;  // 64
    const float* pr = partials + (long)b * (NT2 * 16);

    float tl[16];
#pragma unroll
    for (int j = 0; j < 16; ++j) tl[j] = NEG_INF;
    for (int i = l; i < NT2 * 16; i += 64) {
        float v = pr[i];
        if (v > tl[15]) {
            tl[15] = v;
#pragma unroll
            for (int j = 15; j > 0; --j) {
                float a = tl[j - 1], bb = tl[j];
                if (bb > a) { tl[j - 1] = bb; tl[j] = a; }
            }
        }
    }

    // 16 rounds of wave-max extraction; logsumexp accumulated in-register
    float M = 0.f, S = 0.f;
#pragma unroll 1
    for (int j = 0; j < 16; ++j) {
        float v = tl[0];
        float mx = v;
#pragma unroll
        for (int off = 32; off; off >>= 1) mx = fmaxf(mx, __shfl_xor(mx, off));
        unsigned long long ball = __ballot(v == mx);
        int win = (int)(__ffsll((unsigned long long)ball)) - 1;
        if (l == win) {
#pragma unroll
            for (int q = 0; q < 15; ++q) tl[q] = tl[q + 1];
            tl[15] = NEG_INF;
        }
        if (j == 0) { M = mx; S = 1.0f; }
        else S += expf(mx - M);
    }

    // three fp32 dots: q.e, s.e, s.s
    int lab = labels[b];
    const float4* qr = (const float4*)(q_hat + ((long)b << 9));
    const float4* er = (const float4*)(out_eb + ((long)lab << 9));
    const float4* sr = (const float4*)(sat + ((long)b << 9));
    float a1 = 0.f, a2 = 0.f, a3 = 0.f;
#pragma unroll
    for (int rr = 0; rr < 2; ++rr) {
        int j = 2 * l + rr;
        float4 d4 = qr[j], s4 = sr[j], e4 = er[j];
        a1 += d4.x * e4.x + d4.y * e4.y + d4.z * e4.z + d4.w * e4.w;
        a2 += s4.x * e4.x + s4.y * e4.y + s4.z * e4.z + s4.w * e4.w;
        a3 += s4.x * s4.x + s4.y * s4.y + s4.z * s4.z + s4.w * s4.w;
    }
#pragma unroll
    for (int off = 32; off; off >>= 1) {
        a1 += __shfl_xor(a1, off);
        a2 += __shfl_xor(a2, off);
        a3 += __shfl_xor(a3, off);
    }
    if (l == 0) {
        float invl = inv_norm[lab];
        float pos = a1 * invl * INV_TEMP;
        float mx2 = fmaxf(M, pos);
        float ssum = expf(M - mx2) * S + expf(pos - mx2);
        lnce[b] = logf(ssum) + mx2 - pos;
        float pd = a1 * invl;
        float ps = a2 * invl / fmaxf(sqrtf(a3), 1e-12f);
        lalign[b] = 1.0f - 0.5f * (pd + ps);
    }
}

// ------------------------------------------------------------------- finalize means
__global__ void finalize(const float* __restrict__ lnce, const float* __restrict__ lalign,
                         float* __restrict__ out_losses) {
    __shared__ float s1[256], s2[256];
    int t = threadIdx.x;
    s1[t] = lnce[t] + lnce[t + 256];
    s2[t] = lalign[t] + lalign[t + 256];
    __syncthreads();
    for (int s = 128; s; s >>= 1) {
        if (t < s) { s1[t] += s1[t + s]; s2[t] += s2[t + s]; }
        __syncthreads();
    }
    if (t == 0) {
        out_losses[0] = s1[0] / (float)B_SZ;
        out_losses[1] = s2[0] / (float)B_SZ;
    }
}

extern "C" void kernel_launch(void* const* d_in, const int* in_sizes, int n_in,
                              void* d_out, int out_size, void* d_ws, size_t ws_size,
                              hipStream_t stream) {
    const float* pf = (const float*)d_in[0];
    const float* emb = (const float*)d_in[1];
    const float* sat = (const float*)d_in[2];
    const float* pb = (const float*)d_in[3];
    const float* ebank = (const float*)d_in[4];
    const int* labels = (const int*)d_in[5];

    float* out = (float*)d_out;
    float* out_pb = out;
    float* out_eb = out + PART_BANK_N;
    float* out_losses = out + PART_BANK_N + EMB_BANK_N;

    // ws layout (floats):
    // q_hat 262,144 | inv_norm 20,000 | inv_map 20,000(int) | lnce 512 | lalign 512
    // | partials 512*314*16 | Ab u16 262,144 | Bb u16 10,240,000   (~33 MB total)
    float* ws = (float*)d_ws;
    float* q_hat = ws;
    float* inv_norm = q_hat + (long)B_SZ * DE;
    int* inv_map = (int*)(inv_norm + C_CLASSES);
    float* lnce = (float*)(inv_map + C_CLASSES);
    float* lalign = lnce + B_SZ;
    float* partials = lalign + B_SZ;
    unsigned short* Ab = (unsigned short*)(partials + (long)B_SZ * NT2 * 16);
    unsigned short* Bb = Ab + (long)B_SZ * DE;

    build_map<<<(C_CLASSES + 255) / 256, 256, 0, stream>>>(labels, inv_map);
    embed_qnorm<<<5000 + 128, 256, 0, stream>>>(ebank, emb, inv_map, out_eb, Bb, inv_norm,
                                                q_hat, Ab);
    part_gemm<<<NGEMM + C_CLASSES, 256, 0, stream>>>(Ab, Bb, inv_norm, labels, partials,
                                                     (const float4*)pb, (const float4*)pf,
                                                     inv_map, (float4*)out_pb);
    merge_nce_align<<<B_SZ, 64, 0, stream>>>(partials, q_hat, out_eb, sat, inv_norm,
                                             labels, lnce, lalign);
    finalize<<<1, 256, 0, stream>>>(lnce, lalign, out_losses);
}

// Round 6
// 146.312 us; speedup vs baseline: 1.3534x; 1.0935x over previous
//
#include <hip/hip_runtime.h>
#include <math.h>

#define MOM 0.999f
#define ONE_M_MOM 0.001f
#define INV_TEMP (1.0f / 0.07f)
#define C_CLASSES 20000
#define B_SZ 512
#define DE 512
#define PART_ROW 2048                       // K * Dp = 8 * 256
#define PART_BANK_N (C_CLASSES * PART_ROW)  // 40,960,000 floats
#define EMB_BANK_N (C_CLASSES * DE)         // 10,240,000 floats
#define NEG_INF (-3.0e38f)
#define NTILE 157         // ceil(20000/128)
#define NT2 (NTILE * 2)   // 314 half-tiles per row
#define NGEMM (4 * NTILE) // 628 gemm blocks
#define NPART 2500        // part blocks, 8 rows each

typedef __attribute__((ext_vector_type(8))) short short8;
typedef __attribute__((ext_vector_type(4))) float f32x4;

__device__ inline unsigned short f2bf_rne(float f) {
    unsigned u = __builtin_bit_cast(unsigned, f);
    return (unsigned short)((u + 0x7FFFu + ((u >> 16) & 1u)) >> 16);
}

__device__ inline float bf2f(unsigned short u) {
    return __builtin_bit_cast(float, (unsigned)u << 16);
}

__device__ inline void gload16(const void* g, void* l) {
    __builtin_amdgcn_global_load_lds(
        (const __attribute__((address_space(1))) unsigned int*)g,
        (__attribute__((address_space(3))) unsigned int*)l, 16, 0, 0);
}

// --------- K1: blocks 0..4999 embed bank (1 row/wave, self label-match);
//               blocks 5000..5127 qnorm+conv. Block 0 zeroes the counter.
__global__ void embed_qnorm(const float* __restrict__ ebank, const float* __restrict__ emb,
                            const int* __restrict__ labels, float* __restrict__ out_eb,
                            unsigned short* __restrict__ Bb, float* __restrict__ inv_norm,
                            float* __restrict__ q_hat, unsigned short* __restrict__ Ab,
                            int* __restrict__ counter) {
    int w = threadIdx.x >> 6, l = threadIdx.x & 63;
    int blk = blockIdx.x;
    if (blk == 0 && threadIdx.x == 0) *counter = 0;
    if (blk < 5000) {
        int c = blk * 4 + w;  // < 20000
        // wave-level label match: mb = batch index with label c, else -1
        int m = -1;
#pragma unroll
        for (int k = 0; k < 8; ++k)
            if (labels[l + k * 64] == c) m = l + k * 64;
#pragma unroll
        for (int off = 32; off; off >>= 1) m = max(m, __shfl_xor(m, off));

        const float4* row = (const float4*)(ebank + ((long)c << 9));
        float4 v0 = row[2 * l], v1 = row[2 * l + 1];
        if (m >= 0) {
            const float4* nr = (const float4*)(emb + ((long)m << 9));
            float4 n0 = nr[2 * l], n1 = nr[2 * l + 1];
            v0.x = MOM * v0.x + ONE_M_MOM * n0.x;
            v0.y = MOM * v0.y + ONE_M_MOM * n0.y;
            v0.z = MOM * v0.z + ONE_M_MOM * n0.z;
            v0.w = MOM * v0.w + ONE_M_MOM * n0.w;
            v1.x = MOM * v1.x + ONE_M_MOM * n1.x;
            v1.y = MOM * v1.y + ONE_M_MOM * n1.y;
            v1.z = MOM * v1.z + ONE_M_MOM * n1.z;
            v1.w = MOM * v1.w + ONE_M_MOM * n1.w;
        }
        float4* orow = (float4*)(out_eb + ((long)c << 9));
        orow[2 * l] = v0; orow[2 * l + 1] = v1;
        float ss = v0.x * v0.x + v0.y * v0.y + v0.z * v0.z + v0.w * v0.w
                 + v1.x * v1.x + v1.y * v1.y + v1.z * v1.z + v1.w * v1.w;
#pragma unroll
        for (int off = 32; off; off >>= 1) ss += __shfl_xor(ss, off);
        if (l == 0) inv_norm[c] = 1.0f / fmaxf(sqrtf(ss), 1e-12f);
        short8 o;
        o[0] = (short)f2bf_rne(v0.x); o[1] = (short)f2bf_rne(v0.y);
        o[2] = (short)f2bf_rne(v0.z); o[3] = (short)f2bf_rne(v0.w);
        o[4] = (short)f2bf_rne(v1.x); o[5] = (short)f2bf_rne(v1.y);
        o[6] = (short)f2bf_rne(v1.z); o[7] = (short)f2bf_rne(v1.w);
        *(short8*)(Bb + ((long)c << 9) + l * 8) = o;
    } else {
        int b = (blk - 5000) * 4 + w;  // < 512
        const float4* row = (const float4*)(emb + ((long)b << 9));
        float4 v0 = row[2 * l], v1 = row[2 * l + 1];
        float ss = v0.x * v0.x + v0.y * v0.y + v0.z * v0.z + v0.w * v0.w
                 + v1.x * v1.x + v1.y * v1.y + v1.z * v1.z + v1.w * v1.w;
#pragma unroll
        for (int off = 32; off; off >>= 1) ss += __shfl_xor(ss, off);
        float inv = 1.0f / fmaxf(sqrtf(ss), 1e-12f);
        v0.x *= inv; v0.y *= inv; v0.z *= inv; v0.w *= inv;
        v1.x *= inv; v1.y *= inv; v1.z *= inv; v1.w *= inv;
        float4* outq = (float4*)(q_hat + ((long)b << 9));
        outq[2 * l] = v0; outq[2 * l + 1] = v1;
        short8 o;
        o[0] = (short)f2bf_rne(v0.x); o[1] = (short)f2bf_rne(v0.y);
        o[2] = (short)f2bf_rne(v0.z); o[3] = (short)f2bf_rne(v0.w);
        o[4] = (short)f2bf_rne(v1.x); o[5] = (short)f2bf_rne(v1.y);
        o[6] = (short)f2bf_rne(v1.z); o[7] = (short)f2bf_rne(v1.w);
        *(short8*)(Ab + ((long)b << 9) + l * 8) = o;
    }
}

// --------- K2: blocks [0,628) MFMA GEMM + top-16 partials; [628, 628+2500) part bank
__global__ void __launch_bounds__(256)
part_gemm(const unsigned short* __restrict__ A, const unsigned short* __restrict__ B,
          const float* __restrict__ inv_norm, const int* __restrict__ labels,
          float* __restrict__ partials,
          const float4* __restrict__ pb, const float4* __restrict__ pf,
          float4* __restrict__ out_pb) {
    __shared__ unsigned short smem[128 * 130];  // 33,280 B (shared by both paths)

    if (blockIdx.x >= NGEMM) {
        // ---------------- part bank: 8 rows/block, deep-MLP copy/EMA ----------------
        int c0 = (blockIdx.x - NGEMM) * 8;  // 0..19992
        int t = threadIdx.x;                // 256
        int* mbs = (int*)smem;              // [8]
        if (t < 8) mbs[t] = -1;
        __syncthreads();
        int la = labels[t], lb = labels[t + 256];
#pragma unroll
        for (int r = 0; r < 8; ++r) {
            if (la == c0 + r) mbs[r] = t;
            if (lb == c0 + r) mbs[r] = t + 256;
        }
        __syncthreads();
        const float4* src = pb + (long)c0 * (PART_ROW / 4);
        float4* dst = out_pb + (long)c0 * (PART_ROW / 4);
        float4 v[16];
#pragma unroll
        for (int i = 0; i < 16; ++i) v[i] = src[t + i * 256];  // row = i>>1 (t<256)
#pragma unroll
        for (int i = 0; i < 16; ++i) {
            int mb = mbs[i >> 1];  // wave-uniform
            if (mb >= 0) {
                float4 n = pf[(long)mb * (PART_ROW / 4) + (t + (i & 1) * 256)];
                v[i].x = MOM * v[i].x + ONE_M_MOM * n.x;
                v[i].y = MOM * v[i].y + ONE_M_MOM * n.y;
                v[i].z = MOM * v[i].z + ONE_M_MOM * n.z;
                v[i].w = MOM * v[i].w + ONE_M_MOM * n.w;
            }
            dst[t + i * 256] = v[i];
        }
        return;
    }

    // ---------------- GEMM tile + fused top-16 ----------------
    unsigned short* Asm = smem;          // 128 rows x 64 k = 16 KB
    unsigned short* Bsm = smem + 8192;   // 16 KB

    const int t = threadIdx.x;
    const int w = t >> 6, l = t & 63;
    const int wr = w >> 1, wc = w & 1;

    // bijective XCD-chunked remap of 628 gemm blocks (8 XCDs; q=78, r=4)
    int id = blockIdx.x;
    int xcd = id & 7, idx = id >> 3;
    int wg = (xcd < 4) ? xcd * 79 + idx : 316 + (xcd - 4) * 78 + idx;
    const int bm = wg & 3, bn = wg >> 2;

    f32x4 acc[4][4] = {};

    const int srow = t >> 3;                           // 0..31
    const long swz = ((t & 7) ^ (srow & 7)) << 3;      // pre-swizzled source offset
    const unsigned short* Ag = A + ((long)(bm * 128 + srow) << 9) + swz;
    const unsigned short* Bg[4];
#pragma unroll
    for (int i = 0; i < 4; ++i) {
        int br = bn * 128 + i * 32 + srow;
        if (br > C_CLASSES - 1) br = C_CLASSES - 1;
        Bg[i] = B + ((long)br << 9) + swz;
    }
    char* Adst = (char*)Asm + (w << 10);
    char* Bdst = (char*)Bsm + (w << 10);

    const int fr = l & 15;
    const int s4 = l >> 4;  // 0..3
    const int swr0 = ((s4) ^ (fr & 7)) << 4;
    const int swr1 = ((4 + s4) ^ (fr & 7)) << 4;

    for (int kt = 0; kt < 8; ++kt) {
        const int ko = kt << 6;
#pragma unroll
        for (int i = 0; i < 4; ++i) {
            gload16(Ag + ko + ((long)i << 14), Adst + (i << 12));
            gload16(Bg[i] + ko, Bdst + (i << 12));
        }
        __syncthreads();
        short8 af[2][4], bf[2][4];
        const char* Abase = (const char*)Asm;
        const char* Bbase = (const char*)Bsm;
#pragma unroll
        for (int m = 0; m < 4; ++m) {
            int ra = (wr * 64 + m * 16 + fr) << 7;
            int rb = (wc * 64 + m * 16 + fr) << 7;
            af[0][m] = *(const short8*)(Abase + ra + swr0);
            af[1][m] = *(const short8*)(Abase + ra + swr1);
            bf[0][m] = *(const short8*)(Bbase + rb + swr0);
            bf[1][m] = *(const short8*)(Bbase + rb + swr1);
        }
#pragma unroll
        for (int kk = 0; kk < 2; ++kk)
#pragma unroll
            for (int m = 0; m < 4; ++m)
#pragma unroll
                for (int n = 0; n < 4; ++n)
                    acc[m][n] = __builtin_amdgcn_mfma_f32_16x16x32_bf16(
                        af[kk][m], bf[kk][n], acc[m][n], 0, 0, 0);
        __syncthreads();
    }

    // ---- dump scaled sim into bf16 stile (C/D: col=lane&15, row=(lane>>4)*4+j)
    unsigned short* stile = smem;  // [128][130] bf16
    const int r4 = s4 << 2;
#pragma unroll
    for (int n = 0; n < 4; ++n) {
        int ct = wc * 64 + fr + n * 16;
        int cg = bn * 128 + ct;
        bool ok = cg < C_CLASSES;
        float sc = ok ? inv_norm[cg] * INV_TEMP : 0.0f;
#pragma unroll
        for (int m = 0; m < 4; ++m) {
            int rt = wr * 64 + r4 + m * 16;
#pragma unroll
            for (int j = 0; j < 4; ++j) {
                float v = ok ? acc[m][n][j] * sc : NEG_INF;
                stile[(rt + j) * 130 + ct] = f2bf_rne(v);
            }
        }
    }
    __syncthreads();

    // ---- per-row half-tile top-16
    const int r = t >> 1, half = t & 1;
    const int gr = bm * 128 + r;
    const int lab = labels[gr];
    const int lab_l = lab - (bn << 7) - (half << 6);
    const unsigned short* bp = stile + r * 130 + half * 64;
    float tl[16];
#pragma unroll
    for (int j = 0; j < 16; ++j) tl[j] = NEG_INF;
    for (int c = 0; c < 64; ++c) {
        if (c == lab_l) continue;
        float v = bf2f(bp[c]);
        if (v > tl[15]) {
            tl[15] = v;
#pragma unroll
            for (int j = 15; j > 0; --j) {
                float a = tl[j - 1], bb = tl[j];
                if (bb > a) { tl[j - 1] = bb; tl[j] = a; }
            }
        }
    }
    float* op = partials + ((long)gr * NT2 + (bn << 1) + half) * 16;
#pragma unroll
    for (int j = 0; j < 16; ++j) op[j] = tl[j];
}

// --------- K3: one wave/row merge + logsumexp + align; last block finalizes means
__global__ void __launch_bounds__(64)
merge_fin(const float* __restrict__ partials, const float* __restrict__ q_hat,
          const float* __restrict__ out_eb, const float* __restrict__ sat,
          const float* __restrict__ inv_norm, const int* __restrict__ labels,
          float* __restrict__ lnce, float* __restrict__ lalign,
          int* __restrict__ counter, float* __restrict__ out_losses) {
    int b = blockIdx.x;
    int l = threadIdx.x;  // 64
    const float4* pr4 = (const float4*)(partials + (long)b * (NT2 * 16));

    float tl[16];
#pragma unroll
    for (int j = 0; j < 16; ++j) tl[j] = NEG_INF;
    for (int i = l; i < NT2 * 4; i += 64) {
        float4 v4 = pr4[i];
        float vv[4] = {v4.x, v4.y, v4.z, v4.w};
#pragma unroll
        for (int q = 0; q < 4; ++q) {
            float v = vv[q];
            if (v > tl[15]) {
                tl[15] = v;
#pragma unroll
                for (int j = 15; j > 0; --j) {
                    float a = tl[j - 1], bb = tl[j];
                    if (bb > a) { tl[j - 1] = bb; tl[j] = a; }
                }
            }
        }
    }

    // 16 rounds of wave-max extraction; logsumexp accumulated in-register
    float M = 0.f, S = 0.f;
#pragma unroll 1
    for (int j = 0; j < 16; ++j) {
        float v = tl[0];
        float mx = v;
#pragma unroll
        for (int off = 32; off; off >>= 1) mx = fmaxf(mx, __shfl_xor(mx, off));
        unsigned long long ball = __ballot(v == mx);
        int win = (int)(__ffsll((unsigned long long)ball)) - 1;
        if (l == win) {
#pragma unroll
            for (int q = 0; q < 15; ++q) tl[q] = tl[q + 1];
            tl[15] = NEG_INF;
        }
        if (j == 0) { M = mx; S = 1.0f; }
        else S += expf(mx - M);
    }

    // three fp32 dots: q.e, s.e, s.s
    int lab = labels[b];
    const float4* qr = (const float4*)(q_hat + ((long)b << 9));
    const float4* er = (const float4*)(out_eb + ((long)lab << 9));
    const float4* sr = (const float4*)(sat + ((long)b << 9));
    float a1 = 0.f, a2 = 0.f, a3 = 0.f;
#pragma unroll
    for (int rr = 0; rr < 2; ++rr) {
        int j = 2 * l + rr;
        float4 d4 = qr[j], s4 = sr[j], e4 = er[j];
        a1 += d4.x * e4.x + d4.y * e4.y + d4.z * e4.z + d4.w * e4.w;
        a2 += s4.x * e4.x + s4.y * e4.y + s4.z * e4.z + s4.w * e4.w;
        a3 += s4.x * s4.x + s4.y * s4.y + s4.z * s4.z + s4.w * s4.w;
    }
#pragma unroll
    for (int off = 32; off; off >>= 1) {
        a1 += __shfl_xor(a1, off);
        a2 += __shfl_xor(a2, off);
        a3 += __shfl_xor(a3, off);
    }
    int done = 0;
    if (l == 0) {
        float invl = inv_norm[lab];
        float pos = a1 * invl * INV_TEMP;
        float mx2 = fmaxf(M, pos);
        float ssum = expf(M - mx2) * S + expf(pos - mx2);
        lnce[b] = logf(ssum) + mx2 - pos;
        float pd = a1 * invl;
        float ps = a2 * invl / fmaxf(sqrtf(a3), 1e-12f);
        lalign[b] = 1.0f - 0.5f * (pd + ps);
        __threadfence();
        done = (atomicAdd(counter, 1) == B_SZ - 1) ? 1 : 0;
    }
    done = __shfl(done, 0);
    if (done) {
        __threadfence();
        volatile const float* vn = lnce;
        volatile const float* va = lalign;
        float s1 = 0.f, s2 = 0.f;
#pragma unroll
        for (int k = 0; k < B_SZ / 64; ++k) {
            s1 += vn[l + k * 64];
            s2 += va[l + k * 64];
        }
#pragma unroll
        for (int off = 32; off; off >>= 1) {
            s1 += __shfl_xor(s1, off);
            s2 += __shfl_xor(s2, off);
        }
        if (l == 0) {
            out_losses[0] = s1 / (float)B_SZ;
            out_losses[1] = s2 / (float)B_SZ;
            *counter = 0;  // reset for next replay
        }
    }
}

extern "C" void kernel_launch(void* const* d_in, const int* in_sizes, int n_in,
                              void* d_out, int out_size, void* d_ws, size_t ws_size,
                              hipStream_t stream) {
    const float* pf = (const float*)d_in[0];
    const float* emb = (const float*)d_in[1];
    const float* sat = (const float*)d_in[2];
    const float* pb = (const float*)d_in[3];
    const float* ebank = (const float*)d_in[4];
    const int* labels = (const int*)d_in[5];

    float* out = (float*)d_out;
    float* out_pb = out;
    float* out_eb = out + PART_BANK_N;
    float* out_losses = out + PART_BANK_N + EMB_BANK_N;

    // ws layout (floats):
    // q_hat 262,144 | inv_norm 20,000 | counter 1(int)+pad | lnce 512 | lalign 512
    // | partials 512*314*16 | Ab u16 262,144 | Bb u16 10,240,000
    float* ws = (float*)d_ws;
    float* q_hat = ws;
    float* inv_norm = q_hat + (long)B_SZ * DE;
    int* counter = (int*)(inv_norm + C_CLASSES);
    float* lnce = (float*)(counter + 16);
    float* lalign = lnce + B_SZ;
    float* partials = lalign + B_SZ;
    unsigned short* Ab = (unsigned short*)(partials + (long)B_SZ * NT2 * 16);
    unsigned short* Bb = Ab + (long)B_SZ * DE;

    embed_qnorm<<<5000 + 128, 256, 0, stream>>>(ebank, emb, labels, out_eb, Bb, inv_norm,
                                                q_hat, Ab, counter);
    part_gemm<<<NGEMM + NPART, 256, 0, stream>>>(Ab, Bb, inv_norm, labels, partials,
                                                 (const float4*)pb, (const float4*)pf,
                                                 (float4*)out_pb);
    merge_fin<<<B_SZ, 64, 0, stream>>>(partials, q_hat, out_eb, sat, inv_norm,
                                       labels, lnce, lalign, counter, out_losses);
}